// Round 9
// baseline (153.943 us; speedup 1.0000x reference)
//
#include <hip/hip_runtime.h>
#include <stdint.h>

typedef unsigned int u32;
typedef unsigned short u16;
typedef float f32x4 __attribute__((ext_vector_type(4)));
typedef __fp16 h16x2 __attribute__((ext_vector_type(2)));   // cvt_pkrtz native type
typedef _Float16 f16x8 __attribute__((ext_vector_type(8)));
typedef float f4u __attribute__((ext_vector_type(4), aligned(4)));  // 4B-aligned vec load

#define NB   8
#define CIN  256
#define HH   64
#define WW   64
#define HW   4096
#define COUT 256
#define NPX  128   // pixels per block (2 output rows)
#define BSTR 264   // u16 per Bs row (256 + 8 pad; 528B = 33*16B)

__device__ __forceinline__ u32 pkh(float lo, float hi) {
  h16x2 h = __builtin_amdgcn_cvt_pkrtz(lo, hi);   // v_cvt_pkrtz_f16_f32, 1 instr
  return __builtin_bit_cast(u32, h);
}
union HU { u32 u; h16x2 h; };

// ---- prep_all: blocks 0..511 transpose x -> xT (fp16 NHWC); 512..639 weights ----
// W2f frag layout: frag = (kk*8+cc)*16 + tile; element: lane*8+j ;
// co = tile*16 + (lane&15); c = cc*32 + (lane>>4)*8 + j.
__global__ __launch_bounds__(256) void prep_all(const float* __restrict__ x,
                                                const float* __restrict__ wgt,
                                                u32* __restrict__ xT,
                                                u32* __restrict__ W2f32) {
  int b = blockIdx.x;
  int t = threadIdx.x;
  if (b < 512) {
    __shared__ u32 tile[64][129];
    int n = b >> 6, hw0 = (b & 63) << 6;
    int hw4 = (t & 15) << 2;
    int cp0 = t >> 4;
    const float* xb = x + (size_t)n * CIN * HW + hw0 + hw4;
#pragma unroll
    for (int it = 0; it < 8; ++it) {
      int cp = (it << 4) + cp0;
      int c = cp << 1;
      f4u v0 = *(const f4u*)(xb + (size_t)c * HW);
      f4u v1 = *(const f4u*)(xb + (size_t)(c + 1) * HW);
      tile[hw4 + 0][cp] = pkh(v0.x, v1.x);
      tile[hw4 + 1][cp] = pkh(v0.y, v1.y);
      tile[hw4 + 2][cp] = pkh(v0.z, v1.z);
      tile[hw4 + 3][cp] = pkh(v0.w, v1.w);
    }
    __syncthreads();
    u32* outp = xT + ((size_t)(n * HW + hw0)) * 128;
    int cp = t & 127, hb = t >> 7;
#pragma unroll
    for (int it = 0; it < 32; ++it) {
      int hwl = (it << 1) + hb;
      outp[(size_t)hwl * 128 + cp] = tile[hwl][cp];
    }
  } else {
    // weights: thread = (co, c-pair); reads 18 consecutive floats
    int tt = (b - 512) * 256 + t;   // 32768 total
    int cp = tt & 127, co = tt >> 7;
    int c = cp << 1;
    const float* p = wgt + ((size_t)co * CIN + c) * 9;
    f4u q0 = *(const f4u*)(p + 0);
    f4u q1 = *(const f4u*)(p + 4);
    f4u q2 = *(const f4u*)(p + 8);
    f4u q3 = *(const f4u*)(p + 12);
    float e16 = p[16], e17 = p[17];
    float a0[9], a1[9];
    a0[0]=q0.x; a0[1]=q0.y; a0[2]=q0.z; a0[3]=q0.w;
    a0[4]=q1.x; a0[5]=q1.y; a0[6]=q1.z; a0[7]=q1.w; a0[8]=q2.x;
    a1[0]=q2.y; a1[1]=q2.z; a1[2]=q2.w;
    a1[3]=q3.x; a1[4]=q3.y; a1[5]=q3.z; a1[6]=q3.w; a1[7]=e16; a1[8]=e17;
    int cc = c >> 5;
    int j = (c >> 1) & 3;
    int lane = (co & 15) | (((c >> 3) & 3) << 4);
    int tile_ = ((co >> 6) << 2) | ((co >> 4) & 3);
#pragma unroll
    for (int kk = 0; kk < 9; ++kk) {
      int frag = (kk * 8 + cc) * 16 + tile_;
      W2f32[(size_t)frag * 256 + lane * 4 + j] = pkh(a0[kk], a1[kk]);
    }
  }
}

// ---- main: 256 blocks x 1024 threads; block = 256 Cout x 128 px ----
// 16 waves = 4 strips (64 Cout) x 4 px-quarters (32 px): each B-frag read by
// only 4 waves (was 8) -> LDS B-read traffic halved. No K-split, no reduce.
__global__ __launch_bounds__(1024, 4) void dcn_main(
    const float* __restrict__ offset, const float* __restrict__ mask,
    const float* __restrict__ bias, const u16* __restrict__ xT,
    const u16* __restrict__ W2f, float* __restrict__ out) {
  __shared__ __align__(16) u16 Bs[2][NPX * BSTR];  // 2 x 67.6 KB
  __shared__ __align__(8)  uint2 swl[1152];        // (kk,p): 4 corner wts, fp16 pairs
  __shared__ __align__(8)  ushort4 sol[1152];      // (kk,p): 4 corner position indices

  int bid = blockIdx.x;      // 256 blocks = 1/CU
  int n = bid & 7;           // XCD swizzle: XCD k serves n==k -> 2MB xT slice in L2
  int hp = bid >> 3;         // ho-pair 0..31
  int t = threadIdx.x;
  int lane = t & 63;
  int w = t >> 6;            // wave 0..15

  // 1) sample precompute: 9 taps x 128 px
  for (int i = t; i < 1152; i += 1024) {
    int kk = i >> 7, p = i & 127;
    int ky = kk / 3, kx = kk - ky * 3;
    int sp = (hp << 7) + p;
    int ho = (hp << 1) + (p >> 6);
    float dy = offset[(((size_t)n * 18 + kk * 2 + 0) << 12) + sp];
    float dx = offset[(((size_t)n * 18 + kk * 2 + 1) << 12) + sp];
    float m  = mask  [(((size_t)n * 9  + kk) << 12) + sp];
    float ys = (float)(ky + ho - 1) + dy;
    float xs = (float)(kx + (p & 63) - 1) + dx;
    float y0f = floorf(ys), x0f = floorf(xs);
    float fy = ys - y0f, fx = xs - x0f;
    int y0 = (int)y0f, x0 = (int)x0f;
    int y1 = y0 + 1, x1 = x0 + 1;
    float vy0 = (y0 >= 0 && y0 < HH) ? 1.f : 0.f;
    float vy1 = (y1 >= 0 && y1 < HH) ? 1.f : 0.f;
    float vx0 = (x0 >= 0 && x0 < WW) ? 1.f : 0.f;
    float vx1 = (x1 >= 0 && x1 < WW) ? 1.f : 0.f;
    float w0 = (1.f - fy) * (1.f - fx) * m * vy0 * vx0;
    float w1 = (1.f - fy) * fx * m * vy0 * vx1;
    float w2 = fy * (1.f - fx) * m * vy1 * vx0;
    float w3 = fy * fx * m * vy1 * vx1;
    int iy0 = min(max(y0, 0), HH - 1), iy1 = min(max(y1, 0), HH - 1);
    int ix0 = min(max(x0, 0), WW - 1), ix1 = min(max(x1, 0), WW - 1);
    ushort4 pv;
    pv.x = (u16)((iy0 << 6) + ix0);
    pv.y = (u16)((iy0 << 6) + ix1);
    pv.z = (u16)((iy1 << 6) + ix0);
    pv.w = (u16)((iy1 << 6) + ix1);
    swl[i] = make_uint2(pkh(w0, w1), pkh(w2, w3));
    sol[i] = pv;
  }
  __syncthreads();

  f32x4 acc[4][2];   // 4 Cout tiles (64 co) x 2 px tiles (32 px)
#pragma unroll
  for (int a = 0; a < 4; ++a)
#pragma unroll
    for (int b2 = 0; b2 < 2; ++b2) acc[a][b2] = {0.f, 0.f, 0.f, 0.f};

  const char* xTn = (const char*)xT + ((size_t)n * HW << 9);
  int ml = lane & 15, q = lane >> 4;
  int hw32 = t >> 5;     // half-wave id 0..31: builds px = g*32 + hw32
  int l32 = t & 31;
  int strip = w & 3;     // Cout strip: tiles strip*4 .. strip*4+3
  int pq = w >> 2;       // px-quarter 0..3: px base pq*32
  int tile0 = strip << 2;
  const char* bch = xTn + (l32 << 4);

// accumulate one register-resident corner: 4 v_pk_fma_f16 (8 channels)
#define PKC(G, WD) do {                                                \
    HU a0, a1, a2, a3;                                                 \
    a0.u = (G).x; a1.u = (G).y; a2.u = (G).z; a3.u = (G).w;            \
    s0 = a0.h * (WD) + s0;                                             \
    s1 = a1.h * (WD) + s1;                                             \
    s2 = a2.h * (WD) + s2;                                             \
    s3 = a3.h * (WD) + s3;                                             \
  } while (0)

  // full build of px-group g of tap kk into buf (prologue / reference path)
  auto build0 = [&](int g) {
    int px = (g << 5) + hw32;
    uint2 wu = swl[px];
    ushort4 pv = sol[px];
    HU ua, ub; ua.u = wu.x; ub.u = wu.y;
    h16x2 w0d = __builtin_shufflevector(ua.h, ua.h, 0, 0);
    h16x2 w1d = __builtin_shufflevector(ua.h, ua.h, 1, 1);
    h16x2 w2d = __builtin_shufflevector(ub.h, ub.h, 0, 0);
    h16x2 w3d = __builtin_shufflevector(ub.h, ub.h, 1, 1);
    uint4 G0 = *(const uint4*)(bch + ((int)pv.x << 9));
    uint4 G1 = *(const uint4*)(bch + ((int)pv.y << 9));
    uint4 G2 = *(const uint4*)(bch + ((int)pv.z << 9));
    uint4 G3 = *(const uint4*)(bch + ((int)pv.w << 9));
    h16x2 s0 = {0.f16, 0.f16}, s1 = s0, s2 = s0, s3 = s0;
    PKC(G0, w0d);
    PKC(G1, w1d);
    PKC(G2, w2d);
    PKC(G3, w3d);
    uint4 pkd;
    pkd.x = __builtin_bit_cast(u32, s0); pkd.y = __builtin_bit_cast(u32, s1);
    pkd.z = __builtin_bit_cast(u32, s2); pkd.w = __builtin_bit_cast(u32, s3);
    *(uint4*)((char*)&Bs[0][0] + px * (BSTR * 2) + (l32 << 4)) = pkd;
  };

  // A-fragment load: 4 Cout tiles of flat frag fidx (0..71), from L2
  auto af_load4 = [&](int fidx, f16x8* dst) {
#pragma unroll
    for (int mt = 0; mt < 4; ++mt)
      dst[mt] = *(const f16x8*)(W2f +
                (((size_t)((fidx << 4) + tile0 + mt)) << 9) + (lane << 3));
  };

#pragma unroll
  for (int g = 0; g < 4; ++g) build0(g);

  f16x8 afr[2][4];           // rolling A double-buffer, parity-indexed
  af_load4(0, afr[0]);
  __syncthreads();

#pragma unroll 1
  for (int kk = 0; kk < 9; ++kk) {
    int cur = kk & 1;
    char* Bw = (char*)&Bs[cur ^ 1][0];
    const char* Br = (const char*)&Bs[cur][0];
    int fbase = kk << 3;
#pragma unroll
    for (int g = 0; g < 4; ++g) {
      int px = (g << 5) + hw32;
      uint4 G0, G1, G2, G3;
      if (kk < 8) {        // EARLY: issue next-tap gathers for this px-group
        ushort4 pv = sol[((kk + 1) << 7) + px];
        G0 = *(const uint4*)(bch + ((int)pv.x << 9));
        G1 = *(const uint4*)(bch + ((int)pv.y << 9));
        G2 = *(const uint4*)(bch + ((int)pv.z << 9));
        G3 = *(const uint4*)(bch + ((int)pv.w << 9));
      }
#pragma unroll
      for (int c2 = 0; c2 < 2; ++c2) {
        int cc = (g << 1) | c2;      // compile-time within the unrolled body
        int fidx = fbase + cc;
        int nf = fidx + 1; if (nf > 71) nf = 71;
        af_load4(nf, afr[(cc + 1) & 1]);        // prefetch next K-chunk's A
        f16x8 bf[2];
#pragma unroll
        for (int nt = 0; nt < 2; ++nt)
          bf[nt] = *(const f16x8*)(Br +
                   ((pq << 5) + (nt << 4) + ml) * (BSTR * 2) +
                   (cc << 6) + (q << 4));
#pragma unroll
        for (int mt = 0; mt < 4; ++mt)
#pragma unroll
          for (int nt = 0; nt < 2; ++nt)
            acc[mt][nt] = __builtin_amdgcn_mfma_f32_16x16x32_f16(
                afr[cc & 1][mt], bf[nt], acc[mt][nt], 0, 0, 0);
      }
      if (kk < 8) {        // LATE: pk-combine (vmcnt satisfied) + LDS write
        uint2 wu = swl[((kk + 1) << 7) + px];
        HU ua, ub; ua.u = wu.x; ub.u = wu.y;
        h16x2 w0d = __builtin_shufflevector(ua.h, ua.h, 0, 0);
        h16x2 w1d = __builtin_shufflevector(ua.h, ua.h, 1, 1);
        h16x2 w2d = __builtin_shufflevector(ub.h, ub.h, 0, 0);
        h16x2 w3d = __builtin_shufflevector(ub.h, ub.h, 1, 1);
        h16x2 s0 = {0.f16, 0.f16}, s1 = s0, s2 = s0, s3 = s0;
        PKC(G0, w0d);
        PKC(G1, w1d);
        PKC(G2, w2d);
        PKC(G3, w3d);
        uint4 pkd;
        pkd.x = __builtin_bit_cast(u32, s0); pkd.y = __builtin_bit_cast(u32, s1);
        pkd.z = __builtin_bit_cast(u32, s2); pkd.w = __builtin_bit_cast(u32, s3);
        *(uint4*)(Bw + px * (BSTR * 2) + (l32 << 4)) = pkd;
      }
    }
    __syncthreads();   // all waves done reading Bs[cur] / writing Bs[cur^1]
  }

  // epilogue: D row = q*4+r, col = ml (m91-verified), + bias, direct store
  size_t ob = (size_t)n * COUT * HW + ((size_t)hp << 7);
#pragma unroll
  for (int mt = 0; mt < 4; ++mt) {
#pragma unroll
    for (int r = 0; r < 4; ++r) {
      int co = ((tile0 + mt) << 4) + (q << 2) + r;
      float bv = bias[co];
#pragma unroll
      for (int nt = 0; nt < 2; ++nt) {
        int px = (pq << 5) + (nt << 4) + ml;
        out[ob + (size_t)co * HW + px] = acc[mt][nt][r] + bv;
      }
    }
  }
}

extern "C" void kernel_launch(void* const* d_in, const int* in_sizes, int n_in,
                              void* d_out, int out_size, void* d_ws, size_t ws_size,
                              hipStream_t stream) {
  const float* x      = (const float*)d_in[0];
  const float* offset = (const float*)d_in[1];
  const float* mask   = (const float*)d_in[2];
  const float* weight = (const float*)d_in[3];
  const float* bias   = (const float*)d_in[4];
  float* out = (float*)d_out;

  u16* xT  = (u16*)d_ws;                                      // 16 MB fp16
  u16* W2f = (u16*)((char*)d_ws + (size_t)NB * HW * CIN * 2); // +1.18 MB fp16

  prep_all<<<640, 256, 0, stream>>>(x, weight, (u32*)xT, (u32*)W2f);
  dcn_main<<<256, 1024, 0, stream>>>(offset, mask, bias, xT, W2f, out);
}